// Round 1
// baseline (396.403 us; speedup 1.0000x reference)
//
#include <hip/hip_runtime.h>
#include <hip/hip_bf16.h>

typedef __bf16 bf16;
typedef __bf16 bf16x8 __attribute__((ext_vector_type(8)));
typedef float f32x4 __attribute__((ext_vector_type(4)));

#define SEQ   2048
#define NBAT  4
#define DM    1024
#define NH    16
#define HD    64
#define E3    3072

// ---------------- fp32 -> bf16 convert ----------------
__global__ void cvt_bf16_kernel(const float* __restrict__ in, bf16* __restrict__ out, int n8) {
  int stride = gridDim.x * blockDim.x;
  for (int i = blockIdx.x * blockDim.x + threadIdx.x; i < n8; i += stride) {
    const float4* p = (const float4*)(in + (size_t)i * 8);
    float4 a = p[0];
    float4 b = p[1];
    bf16x8 o;
    o[0] = (bf16)a.x; o[1] = (bf16)a.y; o[2] = (bf16)a.z; o[3] = (bf16)a.w;
    o[4] = (bf16)b.x; o[5] = (bf16)b.y; o[6] = (bf16)b.z; o[7] = (bf16)b.w;
    *(bf16x8*)(out + (size_t)i * 8) = o;
  }
}

// ---------------- QKV projection GEMM: Z = X * W^T + b ----------------
// X: [8192][1024] bf16, W: [3072][1024] bf16, Z: [8192][3072] bf16
#define BM 128
#define BN 128
#define BK 32
#define KSTEPS (DM / BK)

__global__ __launch_bounds__(256, 2) void qkv_gemm_kernel(
    const bf16* __restrict__ A, const bf16* __restrict__ B,
    const float* __restrict__ bias, bf16* __restrict__ Z)
{
  __shared__ bf16 sA[2][BM * BK];
  __shared__ bf16 sB[2][BN * BK];

  const int tid  = threadIdx.x;
  const int lane = tid & 63;
  const int w    = tid >> 6;   // wave 0..3
  const int wr   = w >> 1;
  const int wc   = w & 1;
  const int m0   = blockIdx.x * BM;
  const int n0   = blockIdx.y * BN;

  const f32x4 z4 = {0.f, 0.f, 0.f, 0.f};
  f32x4 acc[4][4];
#pragma unroll
  for (int i = 0; i < 4; ++i)
#pragma unroll
    for (int j = 0; j < 4; ++j)
      acc[i][j] = z4;

  // staging geometry: each wave stages 2KB of sA and 2KB of sB per K-step
  const int srow = w * 32 + (lane >> 2);   // + c*16
  const int skk  = (lane & 3) * 8;
  const bf16* gA = A + (size_t)m0 * DM;
  const bf16* gB = B + (size_t)n0 * DM;

  auto stage = [&](int buf, int t) {
    const int k0 = t * BK;
#pragma unroll
    for (int c = 0; c < 2; ++c)
      __builtin_amdgcn_global_load_lds(
          (const __attribute__((address_space(1))) unsigned int*)(gA + (size_t)(srow + c * 16) * DM + k0 + skk),
          (__attribute__((address_space(3))) unsigned int*)(&sA[buf][w * 1024 + c * 512]),
          16, 0, 0);
#pragma unroll
    for (int c = 0; c < 2; ++c)
      __builtin_amdgcn_global_load_lds(
          (const __attribute__((address_space(1))) unsigned int*)(gB + (size_t)(srow + c * 16) * DM + k0 + skk),
          (__attribute__((address_space(3))) unsigned int*)(&sB[buf][w * 1024 + c * 512]),
          16, 0, 0);
  };

  stage(0, 0);
  int cur = 0;
  const int arow = wr * 64 + (lane & 15);
  const int brow = wc * 64 + (lane & 15);
  const int kf   = (lane >> 4) * 8;

  for (int t = 0; t < KSTEPS; ++t) {
    __syncthreads();                       // buf[cur] staged; prior reads done
    if (t + 1 < KSTEPS) stage(cur ^ 1, t + 1);
    bf16x8 af[4], bfr[4];
#pragma unroll
    for (int i = 0; i < 4; ++i)
      af[i] = *(const bf16x8*)&sA[cur][(arow + i * 16) * BK + kf];
#pragma unroll
    for (int j = 0; j < 4; ++j)
      bfr[j] = *(const bf16x8*)&sB[cur][(brow + j * 16) * BK + kf];
#pragma unroll
    for (int i = 0; i < 4; ++i)
#pragma unroll
      for (int j = 0; j < 4; ++j)
        acc[i][j] = __builtin_amdgcn_mfma_f32_16x16x32_bf16(af[i], bfr[j], acc[i][j], 0, 0, 0);
    cur ^= 1;
  }

  // epilogue: bias add, bf16 store
#pragma unroll
  for (int i = 0; i < 4; ++i) {
#pragma unroll
    for (int j = 0; j < 4; ++j) {
      const int col = n0 + wc * 64 + j * 16 + (lane & 15);
      const float bb = bias[col];
#pragma unroll
      for (int r = 0; r < 4; ++r) {
        const int row = m0 + wr * 64 + i * 16 + (lane >> 4) * 4 + r;
        Z[(size_t)row * E3 + col] = (bf16)(acc[i][j][r] + bb);
      }
    }
  }
}

// ---------------- causal flash attention ----------------
// Z layout per row: [K(0:1024) | Q(1024:2048) | V(2048:3072)], head h at +h*64
#define QB 64
#define KB 64
#define KP 72   // padded leading dim (bf16 elems): 144B stride -> 2-way conflicts only

__global__ __launch_bounds__(256, 2) void attn_kernel(
    const bf16* __restrict__ Z, float* __restrict__ out)
{
  __shared__ bf16 sK[KB][KP];
  __shared__ bf16 sV[HD][KP];      // transposed: sV[d][k]
  __shared__ bf16 sP[4][16][KP];   // per-wave P tile

  const int tid   = threadIdx.x;
  const int lane  = tid & 63;
  const int w     = tid >> 6;
  const int qtile = blockIdx.x;
  const int h     = blockIdx.y;
  const int n     = blockIdx.z;
  const int q0    = qtile * QB;

  const size_t zb = (size_t)n * SEQ * E3;
  const int kcol0 = h * HD;
  const int qcol0 = DM + h * HD;
  const int vcol0 = 2 * DM + h * HD;

  const int l15 = lane & 15;
  const int lhi = lane >> 4;

  // Q fragments held in registers for the whole kernel (wave's 16 q-rows x 64 d)
  bf16x8 qf[2];
  {
    const int qrow = q0 + w * 16 + l15;
#pragma unroll
    for (int kk = 0; kk < 2; ++kk)
      qf[kk] = *(const bf16x8*)&Z[zb + (size_t)qrow * E3 + qcol0 + kk * 32 + lhi * 8];
  }

  const f32x4 z4 = {0.f, 0.f, 0.f, 0.f};
  f32x4 accO[4];
#pragma unroll
  for (int dt = 0; dt < 4; ++dt) accO[dt] = z4;
  float mrow[4] = {-1e30f, -1e30f, -1e30f, -1e30f};
  float lrow[4] = {0.f, 0.f, 0.f, 0.f};

  const float scale = 0.03125f;                 // D^-0.5 = 1/32 (full model dim!)
  const float L2E   = 1.4426950408889634f;

  const int str = tid >> 3;        // 0..31
  const int sc8 = (tid & 7) * 8;   // 0..56

  for (int t = 0; t <= qtile; ++t) {
    __syncthreads();   // previous tile's compute done before restaging
    const size_t kg0 = zb + (size_t)(t * KB) * E3;
#pragma unroll
    for (int half = 0; half < 2; ++half) {
      const int kr = str + half * 32;
      bf16x8 kv = *(const bf16x8*)&Z[kg0 + (size_t)kr * E3 + kcol0 + sc8];
      *(bf16x8*)&sK[kr][sc8] = kv;
      bf16x8 vv = *(const bf16x8*)&Z[kg0 + (size_t)kr * E3 + vcol0 + sc8];
#pragma unroll
      for (int j = 0; j < 8; ++j) sV[sc8 + j][kr] = vv[j];   // transpose into LDS
    }
    __syncthreads();

    // S = Q K^T (16 q-rows x 64 k) per wave
    float s[4][4];
#pragma unroll
    for (int kt = 0; kt < 4; ++kt) {
      f32x4 sa = z4;
#pragma unroll
      for (int kk = 0; kk < 2; ++kk) {
        bf16x8 kfr = *(const bf16x8*)&sK[kt * 16 + l15][kk * 32 + lhi * 8];
        sa = __builtin_amdgcn_mfma_f32_16x16x32_bf16(qf[kk], kfr, sa, 0, 0, 0);
      }
#pragma unroll
      for (int r = 0; r < 4; ++r) s[kt][r] = sa[r] * scale;
    }

    // causal mask only on the diagonal tile
    if (t == qtile) {
#pragma unroll
      for (int kt = 0; kt < 4; ++kt) {
        const int kg = t * KB + kt * 16 + l15;
#pragma unroll
        for (int r = 0; r < 4; ++r) {
          const int qg = q0 + w * 16 + lhi * 4 + r;
          if (kg > qg) s[kt][r] = -1e30f;
        }
      }
    }

    // online softmax: rows live in 16-lane groups (same lane>>4)
#pragma unroll
    for (int r = 0; r < 4; ++r) {
      float mx = fmaxf(fmaxf(s[0][r], s[1][r]), fmaxf(s[2][r], s[3][r]));
      mx = fmaxf(mx, __shfl_xor(mx, 1));
      mx = fmaxf(mx, __shfl_xor(mx, 2));
      mx = fmaxf(mx, __shfl_xor(mx, 4));
      mx = fmaxf(mx, __shfl_xor(mx, 8));
      const float mnew  = fmaxf(mrow[r], mx);
      const float alpha = exp2f((mrow[r] - mnew) * L2E);
      mrow[r] = mnew;
      float ps = 0.f;
#pragma unroll
      for (int kt = 0; kt < 4; ++kt) {
        const float p = exp2f((s[kt][r] - mnew) * L2E);
        s[kt][r] = p;
        ps += p;
      }
      ps += __shfl_xor(ps, 1);
      ps += __shfl_xor(ps, 2);
      ps += __shfl_xor(ps, 4);
      ps += __shfl_xor(ps, 8);
      lrow[r] = lrow[r] * alpha + ps;
#pragma unroll
      for (int dt = 0; dt < 4; ++dt) accO[dt][r] *= alpha;
    }

    // P -> wave-private LDS (C/D layout -> row-major), then PV MFMA
#pragma unroll
    for (int kt = 0; kt < 4; ++kt)
#pragma unroll
      for (int r = 0; r < 4; ++r)
        sP[w][lhi * 4 + r][kt * 16 + l15] = (bf16)s[kt][r];

    asm volatile("s_waitcnt lgkmcnt(0)" ::: "memory");

#pragma unroll
    for (int kk = 0; kk < 2; ++kk) {
      bf16x8 pa = *(const bf16x8*)&sP[w][l15][kk * 32 + lhi * 8];
#pragma unroll
      for (int dt = 0; dt < 4; ++dt) {
        bf16x8 vb = *(const bf16x8*)&sV[dt * 16 + l15][kk * 32 + lhi * 8];
        accO[dt] = __builtin_amdgcn_mfma_f32_16x16x32_bf16(pa, vb, accO[dt], 0, 0, 0);
      }
    }
  }

  // normalize and write fp32 output: out[n][c][h*64 + d]
  const size_t ob = (size_t)n * SEQ * DM;
#pragma unroll
  for (int r = 0; r < 4; ++r) {
    const float inv  = 1.f / lrow[r];
    const int   qrow = q0 + w * 16 + lhi * 4 + r;
#pragma unroll
    for (int dt = 0; dt < 4; ++dt)
      out[ob + (size_t)qrow * DM + h * HD + dt * 16 + l15] = accO[dt][r] * inv;
  }
}

extern "C" void kernel_launch(void* const* d_in, const int* in_sizes, int n_in,
                              void* d_out, int out_size, void* d_ws, size_t ws_size,
                              hipStream_t stream) {
  const float* x    = (const float*)d_in[0];
  const float* W    = (const float*)d_in[1];
  const float* bias = (const float*)d_in[2];
  float* out = (float*)d_out;

  // workspace layout: x_bf16 (16MB) | W_bf16 (6MB) | Z_bf16 (48MB)
  bf16* xb = (bf16*)d_ws;
  bf16* Wb = xb + (size_t)NBAT * SEQ * DM;
  bf16* Zb = Wb + (size_t)E3 * DM;

  cvt_bf16_kernel<<<1024, 256, 0, stream>>>(x, xb, NBAT * SEQ * DM / 8);
  cvt_bf16_kernel<<<512, 256, 0, stream>>>(W, Wb, E3 * DM / 8);

  dim3 g1(NBAT * SEQ / BM, E3 / BN);
  qkv_gemm_kernel<<<g1, 256, 0, stream>>>(xb, Wb, bias, Zb);

  dim3 g2(SEQ / QB, NH, NBAT);
  attn_kernel<<<g2, 256, 0, stream>>>(Zb, out);
}

// Round 2
// 255.776 us; speedup vs baseline: 1.5498x; 1.5498x over previous
//
#include <hip/hip_runtime.h>
#include <hip/hip_bf16.h>

typedef __bf16 bf16;
typedef __bf16 bf16x4 __attribute__((ext_vector_type(4)));
typedef __bf16 bf16x8 __attribute__((ext_vector_type(8)));
typedef float f32x4 __attribute__((ext_vector_type(4)));

#define SEQ   2048
#define NBAT  4
#define DM    1024
#define NH    16
#define HD    64
#define E3    3072

// ---------------- fp32 -> bf16 convert ----------------
__global__ void cvt_bf16_kernel(const float* __restrict__ in, bf16* __restrict__ out, int n8) {
  int stride = gridDim.x * blockDim.x;
  for (int i = blockIdx.x * blockDim.x + threadIdx.x; i < n8; i += stride) {
    const float4* p = (const float4*)(in + (size_t)i * 8);
    float4 a = p[0];
    float4 b = p[1];
    bf16x8 o;
    o[0] = (bf16)a.x; o[1] = (bf16)a.y; o[2] = (bf16)a.z; o[3] = (bf16)a.w;
    o[4] = (bf16)b.x; o[5] = (bf16)b.y; o[6] = (bf16)b.z; o[7] = (bf16)b.w;
    *(bf16x8*)(out + (size_t)i * 8) = o;
  }
}

// ---------------- QKV projection GEMM: Z = X * W^T + b ----------------
#define BM 128
#define BN 128
#define BK 32
#define KSTEPS (DM / BK)

__global__ __launch_bounds__(256, 2) void qkv_gemm_kernel(
    const bf16* __restrict__ A, const bf16* __restrict__ B,
    const float* __restrict__ bias, bf16* __restrict__ Z)
{
  __shared__ bf16 sA[2][BM * BK];
  __shared__ bf16 sB[2][BN * BK];

  const int tid  = threadIdx.x;
  const int lane = tid & 63;
  const int w    = tid >> 6;
  const int wr   = w >> 1;
  const int wc   = w & 1;
  const int m0   = blockIdx.x * BM;
  const int n0   = blockIdx.y * BN;

  const f32x4 z4 = {0.f, 0.f, 0.f, 0.f};
  f32x4 acc[4][4];
#pragma unroll
  for (int i = 0; i < 4; ++i)
#pragma unroll
    for (int j = 0; j < 4; ++j)
      acc[i][j] = z4;

  const int srow = w * 32 + (lane >> 2);
  const int skk  = (lane & 3) * 8;
  const bf16* gA = A + (size_t)m0 * DM;
  const bf16* gB = B + (size_t)n0 * DM;

  auto stage = [&](int buf, int t) {
    const int k0 = t * BK;
#pragma unroll
    for (int c = 0; c < 2; ++c)
      __builtin_amdgcn_global_load_lds(
          (const __attribute__((address_space(1))) unsigned int*)(gA + (size_t)(srow + c * 16) * DM + k0 + skk),
          (__attribute__((address_space(3))) unsigned int*)(&sA[buf][w * 1024 + c * 512]),
          16, 0, 0);
#pragma unroll
    for (int c = 0; c < 2; ++c)
      __builtin_amdgcn_global_load_lds(
          (const __attribute__((address_space(1))) unsigned int*)(gB + (size_t)(srow + c * 16) * DM + k0 + skk),
          (__attribute__((address_space(3))) unsigned int*)(&sB[buf][w * 1024 + c * 512]),
          16, 0, 0);
  };

  stage(0, 0);
  int cur = 0;
  const int arow = wr * 64 + (lane & 15);
  const int brow = wc * 64 + (lane & 15);
  const int kf   = (lane >> 4) * 8;

  for (int t = 0; t < KSTEPS; ++t) {
    __syncthreads();
    if (t + 1 < KSTEPS) stage(cur ^ 1, t + 1);
    bf16x8 af[4], bfr[4];
#pragma unroll
    for (int i = 0; i < 4; ++i)
      af[i] = *(const bf16x8*)&sA[cur][(arow + i * 16) * BK + kf];
#pragma unroll
    for (int j = 0; j < 4; ++j)
      bfr[j] = *(const bf16x8*)&sB[cur][(brow + j * 16) * BK + kf];
#pragma unroll
    for (int i = 0; i < 4; ++i)
#pragma unroll
      for (int j = 0; j < 4; ++j)
        acc[i][j] = __builtin_amdgcn_mfma_f32_16x16x32_bf16(af[i], bfr[j], acc[i][j], 0, 0, 0);
    cur ^= 1;
  }

#pragma unroll
  for (int i = 0; i < 4; ++i) {
#pragma unroll
    for (int j = 0; j < 4; ++j) {
      const int col = n0 + wc * 64 + j * 16 + (lane & 15);
      const float bb = bias[col];
#pragma unroll
      for (int r = 0; r < 4; ++r) {
        const int row = m0 + wr * 64 + i * 16 + (lane >> 4) * 4 + r;
        Z[(size_t)row * E3 + col] = (bf16)(acc[i][j][r] + bb);
      }
    }
  }
}

// ---------------- causal flash attention ----------------
// Z layout per row: [K(0:1024) | Q(1024:2048) | V(2048:3072)], head h at +h*64
// Swapped QK^T: S^T = K·Q^T so q = lane&15 everywhere; PV as O^T = V^T·P^T.
#define QB 128
#define KB 64
#define KP 72   // padded LDS stride (bf16): 144B

__global__ __launch_bounds__(256, 2) void attn_kernel(
    const bf16* __restrict__ Z, float* __restrict__ out)
{
  __shared__ bf16 sK[KB][KP];
  __shared__ bf16 sVrow[KB][KP];
  __shared__ bf16 sVT[HD][KP];        // sVT[d][k]
  __shared__ bf16 sP[4][2][16][KP];   // [wave][qs][q][k]

  const int tid   = threadIdx.x;
  const int lane  = tid & 63;
  const int w     = tid >> 6;
  const int l15   = lane & 15;
  const int lhi   = lane >> 4;
  const int qtile = blockIdx.x;
  const int h     = blockIdx.y;
  const int n     = blockIdx.z;
  const int q0    = qtile * QB;

  const size_t zb = (size_t)n * SEQ * E3;
  const int kcol0 = h * HD;
  const int qcol0 = DM + h * HD;
  const int vcol0 = 2 * DM + h * HD;

  // Q fragments (B-operand of swapped QK^T): lane holds Q[q=l15][d=kk*32+lhi*8 ..+7]
  bf16x8 qf[2][2];
#pragma unroll
  for (int qs = 0; qs < 2; ++qs) {
    const int qrow = q0 + w * 32 + qs * 16 + l15;
#pragma unroll
    for (int kk = 0; kk < 2; ++kk)
      qf[qs][kk] = *(const bf16x8*)&Z[zb + (size_t)qrow * E3 + qcol0 + kk * 32 + lhi * 8];
  }

  const f32x4 z4 = {0.f, 0.f, 0.f, 0.f};
  f32x4 accO[2][4];   // [qs][dt]: O^T[d=dt*16+lhi*4+r][q=l15]
#pragma unroll
  for (int qs = 0; qs < 2; ++qs)
#pragma unroll
    for (int dt = 0; dt < 4; ++dt) accO[qs][dt] = z4;
  float mrow[2] = {-1e30f, -1e30f};
  float lrow[2] = {0.f, 0.f};

  const float scale = 0.03125f;   // D^-0.5 = 1/32 (full model dim)
  const float L2E   = 1.4426950408889634f;

  // staging map: 2 chunks each of K and V rows
  const int c0row = tid >> 3;          // 0..31
  const int c0col = (tid & 7) * 8;
  // transpose map: thread owns column d=td, k rows [tk0, tk0+16)
  const int td  = tid & 63;
  const int tk0 = (tid >> 6) * 16;

  const int ntiles = (q0 + QB) / KB;   // 2*qtile + 2
  const int qwave  = q0 + w * 32;      // wave's first q-row

  for (int t = 0; t < ntiles; ++t) {
    __syncthreads();   // previous tile's reads of sK/sVT/sVrow complete
    const size_t g0 = zb + (size_t)(t * KB) * E3;
#pragma unroll
    for (int c = 0; c < 2; ++c) {
      const int row = c0row + c * 32;
      bf16x8 kv = *(const bf16x8*)&Z[g0 + (size_t)row * E3 + kcol0 + c0col];
      *(bf16x8*)&sK[row][c0col] = kv;
      bf16x8 vv = *(const bf16x8*)&Z[g0 + (size_t)row * E3 + vcol0 + c0col];
      *(bf16x8*)&sVrow[row][c0col] = vv;
    }
    __syncthreads();   // staging visible

    // conflict-free V transpose: read a column (lanes -> consecutive addrs), write rows
    {
      bf16 tv[16];
#pragma unroll
      for (int j = 0; j < 16; ++j) tv[j] = sVrow[tk0 + j][td];
      *(bf16x8*)&sVT[td][tk0]     = *(bf16x8*)&tv[0];
      *(bf16x8*)&sVT[td][tk0 + 8] = *(bf16x8*)&tv[8];
    }
    __syncthreads();   // sVT complete

    if (t * KB <= qwave + 31) {        // at least one unmasked k for this wave
      // S^T = K·Q^T : C[k_local=lhi*4+r][q=l15] per kt
      f32x4 st[2][4];
#pragma unroll
      for (int qs = 0; qs < 2; ++qs)
#pragma unroll
        for (int kt = 0; kt < 4; ++kt) st[qs][kt] = z4;
#pragma unroll
      for (int kt = 0; kt < 4; ++kt)
#pragma unroll
        for (int kk = 0; kk < 2; ++kk) {
          bf16x8 kf = *(const bf16x8*)&sK[kt * 16 + l15][kk * 32 + lhi * 8];
#pragma unroll
          for (int qs = 0; qs < 2; ++qs)
            st[qs][kt] = __builtin_amdgcn_mfma_f32_16x16x32_bf16(kf, qf[qs][kk], st[qs][kt], 0, 0, 0);
        }

      const bool needmask = (t * KB + KB - 1) > qwave;

#pragma unroll
      for (int qs = 0; qs < 2; ++qs) {
        const int qg = qwave + qs * 16 + l15;
        float sv[16];
#pragma unroll
        for (int kt = 0; kt < 4; ++kt)
#pragma unroll
          for (int r = 0; r < 4; ++r) {
            float x = st[qs][kt][r] * scale;
            if (needmask) {
              const int kg = t * KB + kt * 16 + lhi * 4 + r;
              if (kg > qg) x = -1e30f;
            }
            sv[kt * 4 + r] = x;
          }
        // row max: 15 in-lane + 2 shfl (row q spread over lanes l15, l15+16, +32, +48)
        float mx = sv[0];
#pragma unroll
        for (int i = 1; i < 16; ++i) mx = fmaxf(mx, sv[i]);
        mx = fmaxf(mx, __shfl_xor(mx, 16));
        mx = fmaxf(mx, __shfl_xor(mx, 32));
        const float mnew  = fmaxf(mrow[qs], mx);
        const float alpha = exp2f((mrow[qs] - mnew) * L2E);
        mrow[qs] = mnew;
        float ps = 0.f;
        bf16 pb[16];
#pragma unroll
        for (int i = 0; i < 16; ++i) {
          const float p = exp2f((sv[i] - mnew) * L2E);
          pb[i] = (bf16)p;
          ps += p;
        }
        ps += __shfl_xor(ps, 16);
        ps += __shfl_xor(ps, 32);
        lrow[qs] = lrow[qs] * alpha + ps;
#pragma unroll
        for (int dt = 0; dt < 4; ++dt) accO[qs][dt] *= alpha;
        // P store: 4 consecutive k per write (vector b64)
#pragma unroll
        for (int kt = 0; kt < 4; ++kt) {
          bf16x4 pk = {pb[kt * 4], pb[kt * 4 + 1], pb[kt * 4 + 2], pb[kt * 4 + 3]};
          *(bf16x4*)&sP[w][qs][l15][kt * 16 + lhi * 4] = pk;
        }
      }
      asm volatile("s_waitcnt lgkmcnt(0)" ::: "memory");
      __builtin_amdgcn_sched_barrier(0);

      // O^T += V^T·P^T : A = sVT rows, B = sP rows
#pragma unroll
      for (int kk = 0; kk < 2; ++kk) {
        bf16x8 pfr[2];
#pragma unroll
        for (int qs = 0; qs < 2; ++qs)
          pfr[qs] = *(const bf16x8*)&sP[w][qs][l15][kk * 32 + lhi * 8];
#pragma unroll
        for (int dt = 0; dt < 4; ++dt) {
          bf16x8 vf = *(const bf16x8*)&sVT[dt * 16 + l15][kk * 32 + lhi * 8];
#pragma unroll
          for (int qs = 0; qs < 2; ++qs)
            accO[qs][dt] = __builtin_amdgcn_mfma_f32_16x16x32_bf16(vf, pfr[qs], accO[qs][dt], 0, 0, 0);
        }
      }
    }
  }

  // epilogue: normalize, float4 stores (d = dt*16 + lhi*4 + r)
  const size_t ob = (size_t)n * SEQ * DM;
#pragma unroll
  for (int qs = 0; qs < 2; ++qs) {
    const float inv  = 1.f / lrow[qs];
    const int   qrow = qwave + qs * 16 + l15;
#pragma unroll
    for (int dt = 0; dt < 4; ++dt) {
      float4 o;
      o.x = accO[qs][dt][0] * inv;
      o.y = accO[qs][dt][1] * inv;
      o.z = accO[qs][dt][2] * inv;
      o.w = accO[qs][dt][3] * inv;
      *(float4*)&out[ob + (size_t)qrow * DM + h * HD + dt * 16 + lhi * 4] = o;
    }
  }
}

extern "C" void kernel_launch(void* const* d_in, const int* in_sizes, int n_in,
                              void* d_out, int out_size, void* d_ws, size_t ws_size,
                              hipStream_t stream) {
  const float* x    = (const float*)d_in[0];
  const float* W    = (const float*)d_in[1];
  const float* bias = (const float*)d_in[2];
  float* out = (float*)d_out;

  bf16* xb = (bf16*)d_ws;
  bf16* Wb = xb + (size_t)NBAT * SEQ * DM;
  bf16* Zb = Wb + (size_t)E3 * DM;

  cvt_bf16_kernel<<<1024, 256, 0, stream>>>(x, xb, NBAT * SEQ * DM / 8);
  cvt_bf16_kernel<<<512, 256, 0, stream>>>(W, Wb, E3 * DM / 8);

  dim3 g1(NBAT * SEQ / BM, E3 / BN);
  qkv_gemm_kernel<<<g1, 256, 0, stream>>>(xb, Wb, bias, Zb);

  dim3 g2(SEQ / QB, NH, NBAT);
  attn_kernel<<<g2, 256, 0, stream>>>(Zb, out);
}